// Round 4
// baseline (232.431 us; speedup 1.0000x reference)
//
#include <hip/hip_runtime.h>

#define D 512
#define NS 4096
#define NROWS 8192
#define NB_XX 272                 // sum_{bi<32} (16 - bi/2)
#define NB_GEMM (2 * NB_XX + 512) // 272+272+512 = 1056 (= 8*132)
#define LDSS 24576                // shorts per buffer: Ahi 8KB|Alo 8KB|Bhi 16KB|Blo 16KB

typedef __attribute__((ext_vector_type(8))) short bf16x8;
typedef __attribute__((ext_vector_type(4))) float f32x4;

__device__ __forceinline__ unsigned short f2bf(float f) {
  unsigned int u = __float_as_uint(f);
  u += 0x7fffu + ((u >> 16) & 1u);        // RNE
  return (unsigned short)(u >> 16);
}
__device__ __forceinline__ float bf2f(unsigned short h) {
  return __uint_as_float(((unsigned int)h) << 16);
}
__device__ __forceinline__ void gload_lds16(const void* g, void* l) {
  __builtin_amdgcn_global_load_lds(
      (const __attribute__((address_space(1))) unsigned int*)g,
      (__attribute__((address_space(3))) unsigned int*)l, 16, 0, 0);
}
#define WAITV(N) asm volatile("s_waitcnt vmcnt(" #N ")" ::: "memory")

// ---------------- k_pre: row L2 norm -> sq, bf16 hi/lo split, per-block col partials ----
// 64 blocks x 512 threads; wave w handles rows blk*128 + w*16 + [0,16).
__global__ __launch_bounds__(512) void k_pre(const float* __restrict__ src,
                                             const float* __restrict__ tgt,
                                             float* __restrict__ sq,
                                             unsigned short* __restrict__ hi,
                                             unsigned short* __restrict__ lo,
                                             float* __restrict__ Spart) {
  int t = threadIdx.x, w = t >> 6, l = t & 63;
  float csum[8] = {0.f, 0.f, 0.f, 0.f, 0.f, 0.f, 0.f, 0.f};
  for (int i = 0; i < 16; ++i) {
    int r = blockIdx.x * 128 + w * 16 + i;
    const float* p = (r < NS) ? (src + (size_t)r * D) : (tgt + (size_t)(r - NS) * D);
    float4 v0 = *(const float4*)(p + l * 8);
    float4 v1 = *(const float4*)(p + l * 8 + 4);
    float x[8] = {v0.x, v0.y, v0.z, v0.w, v1.x, v1.y, v1.z, v1.w};
    float s = 0.f;
    #pragma unroll
    for (int j = 0; j < 8; ++j) s += x[j] * x[j];
    #pragma unroll
    for (int off = 1; off < 64; off <<= 1) s += __shfl_xor(s, off);
    float iv = 1.0f / fmaxf(sqrtf(s), 1e-12f);
    if (l == 0) sq[r] = s * iv * iv;
    unsigned short hs[8], ls[8];
    #pragma unroll
    for (int j = 0; j < 8; ++j) {
      float xn = x[j] * iv;
      unsigned short h = f2bf(xn);
      hs[j] = h;
      ls[j] = f2bf(xn - bf2f(h));
      csum[j] += xn;
    }
    *(uint4*)&hi[(size_t)r * D + l * 8] = *(uint4*)hs;
    *(uint4*)&lo[(size_t)r * D + l * 8] = *(uint4*)ls;
  }
  __shared__ float cs[8][512];
  #pragma unroll
  for (int j = 0; j < 8; ++j) cs[w][l * 8 + j] = csum[j];
  __syncthreads();
  float a = 0.f;
  #pragma unroll
  for (int ww = 0; ww < 8; ++ww) a += cs[ww][t];
  Spart[blockIdx.x * 512 + t] = a;
}

// ---------------- k_prep: bandwidth closed form -> 5 exp2 coefs; zero accumulators ------
__global__ __launch_bounds__(512) void k_prep(const float* __restrict__ sq,
                                              const float* __restrict__ Spart,
                                              float* __restrict__ na,
                                              double* __restrict__ dsum,
                                              unsigned int* __restrict__ cnt) {
  int t = threadIdx.x;
  double ssq = 0.0;
  for (int i = t; i < NROWS; i += 512) ssq += (double)sq[i];
  double cssum = 0.0;
  for (int b = 0; b < 64; ++b) cssum += (double)Spart[b * 512 + t];
  double ss2 = cssum * cssum;
  #pragma unroll
  for (int off = 32; off; off >>= 1) {
    ssq += __shfl_down(ssq, off);
    ss2 += __shfl_down(ss2, off);
  }
  __shared__ double l1[8], l2[8];
  if ((t & 63) == 0) { l1[t >> 6] = ssq; l2[t >> 6] = ss2; }
  __syncthreads();
  if (t == 0) {
    double SSQ = 0.0, SS2 = 0.0;
    #pragma unroll
    for (int i = 0; i < 8; ++i) { SSQ += l1[i]; SS2 += l2[i]; }
    double n = (double)NROWS;
    double sum_d2 = 2.0 * n * SSQ - 2.0 * SS2;
    double bw = sum_d2 / (n * n - n) + 1e-8;     // + EPS
    bw = bw * 0.25;                               // / KERNEL_MUL^(KERNEL_NUM//2)
    const double LOG2E = 1.4426950408889634;
    #pragma unroll
    for (int m = 0; m < 5; ++m) na[m] = (float)(-LOG2E / (bw * (double)(1 << m)));
    dsum[0] = 0.0; dsum[1] = 0.0; dsum[2] = 0.0;
    cnt[0] = 0u;
  }
}

// ---------------- k_gemm: 128x256 brick, 8 waves, 3-buf ring, counted vmcnt -------------
// Per K-step(32): stage 48KB (A 128 rows, B 256 rows; hi+lo), each wave 48 MFMA (64x64 out).
// Swizzle: LDS slot (row, c) holds global chunk c ^ ((row>>1)&3); linear dest, pre-swizzled
// source, XOR on read (rule 21).
__global__ __launch_bounds__(512, 2) void k_gemm(const unsigned short* __restrict__ hi,
                                                 const unsigned short* __restrict__ lo,
                                                 const float* __restrict__ sq,
                                                 const float* __restrict__ na,
                                                 double* __restrict__ dsum,
                                                 unsigned int* __restrict__ cnt,
                                                 float* __restrict__ out) {
  __shared__ unsigned short lds[3 * LDSS];
  __shared__ double red[8];

  int bid0 = blockIdx.x;
  int bid = (bid0 & 7) * (NB_GEMM / 8) + (bid0 >> 3);   // XCD swizzle (1056 % 8 == 0)
  int type, bi, c2;
  if (bid < 2 * NB_XX) {
    type = (bid >= NB_XX);
    int idx = bid - type * NB_XX;
    int b = 0;
    while (idx >= 16 - (b >> 1)) { idx -= 16 - (b >> 1); ++b; }
    bi = b;
    c2 = (b >> 1) + idx;
  } else {
    type = 2;
    int rem = bid - 2 * NB_XX;
    bi = rem >> 4;
    c2 = rem & 15;
  }
  int offA = (type == 1) ? NS : 0;       // rows: src for XX/XY, tgt for YY
  int offB = (type == 0) ? 0 : NS;       // cols: src for XX, tgt for YY/XY
  bool sym = (type < 2);

  int t = threadIdx.x;
  int w = t >> 6, l = t & 63;
  int wr = w >> 2, wc = w & 3;           // 2 x 4 wave grid, each wave 64x64
  int fr = l & 15, fk = l >> 4;

  // ---- staging map: 48 regions of 512 shorts; wave w owns regions w*6..w*6+5 ----
  // region r: r<8 Ahi rows r*16.. | r<16 Alo | r<32 Bhi rows (r-16)*16 | r<48 Blo
  const unsigned short* gsrc[6];
  int ldsoff[6];
  #pragma unroll
  for (int c = 0; c < 6; ++c) {
    int r = w * 6 + c;
    int isB = (r >= 16);
    int isLo = isB ? (r >= 32) : (r >= 8);
    int rr = isB ? ((r - 16) & 15) : (r & 7);
    int rowbase = isB ? (offB + c2 * 256 + rr * 16) : (offA + bi * 128 + rr * 16);
    const unsigned short* arr = isLo ? lo : hi;
    int gswz = ((l & 3) ^ ((l >> 3) & 3)) * 8;           // pre-swizzled source chunk
    gsrc[c] = arr + (size_t)(rowbase + (l >> 2)) * D + gswz;
    ldsoff[c] = r * 512;
  }

  int rsw = (fr >> 1) & 3;
  int aoff = (wr * 64 + fr) * 32 + (fk ^ rsw) * 8;            // Ahi; +4096 for Alo; +m*512
  int boff = 8192 + (wc * 64 + fr) * 32 + (fk ^ rsw) * 8;     // Bhi; +8192 for Blo; +n*512

  f32x4 acc[4][4];
  f32x4 zero = {0.f, 0.f, 0.f, 0.f};
  #pragma unroll
  for (int m = 0; m < 4; ++m)
    #pragma unroll
    for (int n = 0; n < 4; ++n) acc[m][n] = zero;

  // ---- prologue: stage K-steps 0,1 into slots 0,1 ----
  #pragma unroll
  for (int c = 0; c < 6; ++c) gload_lds16(gsrc[c], &lds[ldsoff[c]]);
  #pragma unroll
  for (int c = 0; c < 6; ++c) gload_lds16(gsrc[c] + 32, &lds[LDSS + ldsoff[c]]);

  unsigned int b0 = 0, b1 = LDSS, b2 = 2 * LDSS;   // read / landing / issue slots
  for (int kt = 0; kt < 16; ++kt) {
    if (kt < 15) { WAITV(6); } else { WAITV(0); }  // own 6 loads for step kt retired
    __builtin_amdgcn_s_barrier();                  // all waves' loads for kt visible
    __builtin_amdgcn_sched_barrier(0);

    bf16x8 ah[4], al[4], bh[4], bl[4];
    #pragma unroll
    for (int m = 0; m < 4; ++m) {
      ah[m] = *(const bf16x8*)&lds[b0 + aoff + m * 512];
      al[m] = *(const bf16x8*)&lds[b0 + 4096 + aoff + m * 512];
    }
    #pragma unroll
    for (int n = 0; n < 4; ++n) {
      bh[n] = *(const bf16x8*)&lds[b0 + boff + n * 512];
      bl[n] = *(const bf16x8*)&lds[b0 + 8192 + boff + n * 512];
    }
    if (kt < 14) {                                 // issue step kt+2 into slot b2 (WAR-safe)
      #pragma unroll
      for (int c = 0; c < 6; ++c)
        gload_lds16(gsrc[c] + (kt + 2) * 32, &lds[b2 + ldsoff[c]]);
    }
    __builtin_amdgcn_s_setprio(1);
    #pragma unroll
    for (int m = 0; m < 4; ++m)
      #pragma unroll
      for (int n = 0; n < 4; ++n) {
        acc[m][n] = __builtin_amdgcn_mfma_f32_16x16x32_bf16(ah[m], bh[n], acc[m][n], 0, 0, 0);
        acc[m][n] = __builtin_amdgcn_mfma_f32_16x16x32_bf16(ah[m], bl[n], acc[m][n], 0, 0, 0);
        acc[m][n] = __builtin_amdgcn_mfma_f32_16x16x32_bf16(al[m], bh[n], acc[m][n], 0, 0, 0);
      }
    __builtin_amdgcn_s_setprio(0);
    unsigned int tmp = b0; b0 = b1; b1 = b2; b2 = tmp;   // rotate ring
  }

  // ---- epilogue (R2-proven numerics): 5 exp2 per entry, per-entry f64 accumulate ----
  float nam[5];
  #pragma unroll
  for (int m2 = 0; m2 < 5; ++m2) nam[m2] = na[m2];
  int giL0 = bi * 128 + wr * 64;           // matrix-local row base
  int gjL0 = c2 * 256 + wc * 64;           // matrix-local col base
  float sqa[4][4], sqb[4];
  #pragma unroll
  for (int m = 0; m < 4; ++m)
    #pragma unroll
    for (int j = 0; j < 4; ++j) sqa[m][j] = sq[offA + giL0 + m * 16 + fk * 4 + j];
  #pragma unroll
  for (int n = 0; n < 4; ++n) sqb[n] = sq[offB + gjL0 + n * 16 + fr];

  double local = 0.0;
  #pragma unroll
  for (int m = 0; m < 4; ++m)
    #pragma unroll
    for (int n = 0; n < 4; ++n) {
      int gjL = gjL0 + n * 16 + fr;
      #pragma unroll
      for (int j = 0; j < 4; ++j) {
        int giL = giL0 + m * 16 + fk * 4 + j;
        float d2 = fmaxf(fmaf(-2.f, acc[m][n][j], sqa[m][j] + sqb[n]), 0.f);
        float kv = 0.f;
        #pragma unroll
        for (int m2 = 0; m2 < 5; ++m2) kv += __builtin_amdgcn_exp2f(d2 * nam[m2]);
        float wf = sym ? ((gjL > giL) ? 2.f : ((gjL == giL) ? 1.f : 0.f)) : 1.f;
        local += (double)(wf * kv);
      }
    }
  #pragma unroll
  for (int off = 32; off; off >>= 1) local += __shfl_down(local, off);
  if (l == 0) red[w] = local;
  __syncthreads();
  if (t == 0) {
    double bsum = 0.0;
    #pragma unroll
    for (int i = 0; i < 8; ++i) bsum += red[i];
    atomicAdd(&dsum[type], bsum);
    __threadfence();
    unsigned int ticket = atomicAdd(cnt, 1u);
    if (ticket == NB_GEMM - 1) {           // last block computes the loss
      __threadfence();
      double A0 = dsum[0], A1 = dsum[1], A2 = dsum[2];
      double ns = (double)NS;
      double loss = (A0 - 5.0 * ns) / (ns * (ns - 1.0))
                  + (A1 - 5.0 * ns) / (ns * (ns - 1.0))
                  - 2.0 * A2 / (ns * ns);
      out[0] = (float)loss;
    }
  }
}

extern "C" void kernel_launch(void* const* d_in, const int* in_sizes, int n_in,
                              void* d_out, int out_size, void* d_ws, size_t ws_size,
                              hipStream_t stream) {
  (void)in_sizes; (void)n_in; (void)out_size; (void)ws_size;
  const float* src = (const float*)d_in[0];
  const float* tgt = (const float*)d_in[1];
  float* out = (float*)d_out;
  char* ws = (char*)d_ws;

  // ws layout:
  float*          sq    = (float*)(ws);                       // 32 KB
  float*          Spart = (float*)(ws + 0x8000);              // 128 KB
  float*          na    = (float*)(ws + 0x28000);             // 20 B
  double*         dsum  = (double*)(ws + 0x28040);            // 24 B
  unsigned int*   cnt   = (unsigned int*)(ws + 0x28080);      // 4 B
  unsigned short* hi    = (unsigned short*)(ws + 0x100000);   // 8 MB
  unsigned short* lo    = (unsigned short*)(ws + 0x900000);   // 8 MB

  hipLaunchKernelGGL(k_pre, dim3(64), dim3(512), 0, stream, src, tgt, sq, hi, lo, Spart);
  hipLaunchKernelGGL(k_prep, dim3(1), dim3(512), 0, stream, sq, Spart, na, dsum, cnt);
  hipLaunchKernelGGL(k_gemm, dim3(NB_GEMM), dim3(512), 0, stream, hi, lo, sq, na, dsum, cnt, out);
}